// Round 18
// baseline (820.109 us; speedup 1.0000x reference)
//
#include <hip/hip_runtime.h>

#define CN0 100000
#define CN1 300000
#define CN2 200000
#define EA0 600000
#define EA1 1200000
#define EC2 600000
#define EB1 600000
#define EB2 600000
#define TOTSEG (2*CN0 + 3*CN1 + 2*CN2)           // 1,500,000
#define OVCAP 16384

typedef __attribute__((ext_vector_type(8))) short short8;
typedef __attribute__((ext_vector_type(4))) float f32x4;
typedef __attribute__((ext_vector_type(8))) unsigned short u16x8;

__device__ __forceinline__ float lrelu(float v) { return v >= 0.f ? v : 0.2f * v; }
__device__ __forceinline__ unsigned short btop(float x) {
    return (unsigned short)(__float_as_uint(x) >> 16);
}
__device__ __forceinline__ unsigned short f2bf(float x) {  // RTN f32->bf16
    unsigned u = __float_as_uint(x);
    return (unsigned short)((u + 0x7FFFu + ((u >> 16) & 1u)) >> 16);
}
__device__ __forceinline__ float bf2f(unsigned short b) {
    return __uint_as_float((unsigned)b << 16);
}

struct Pats {
    const int* seg[7];
    const int* vidx[7];
    int E[7];
    int base[7];
    int K[7];
    int eoff[7];
};

struct MMJob {
    const float* X; const float* W; const float* a;
    unsigned short* Y; float* p; float* q; int nchunk;
};

struct MMT {
    const float* X;
    const float* W1; const float* a1; unsigned short* Y1; float* p1; float* q1;
    const float* W2; const float* a2; unsigned short* Y2; float* p2; float* q2;
    const float* uuv; float* pv; int nchunk;
};

struct AggTask {
    int baseA, KA, eoffA;
    const float* psA; const float* pvA; const unsigned short* MbA;
    int baseB, KB, eoffB;   // baseB < 0 => single-pattern task
    const float* psB; const float* pvB; const unsigned short* MbB;
    float* out; int nseg;
};

// ---------------- shared single-W MFMA body (bf16x3 split) ----------------
__device__ __forceinline__ void mm_body(const float* __restrict__ X, const float* __restrict__ W,
                                        const float* __restrict__ a, unsigned short* __restrict__ Yb,
                                        float* __restrict__ p, float* __restrict__ q,
                                        int nchunk, int wid, int nw, int lane) {
    int l15 = lane & 15, lq = lane >> 4;
    short8 bh[4][2], bl[4][2];
#pragma unroll
    for (int t = 0; t < 4; ++t)
#pragma unroll
        for (int h = 0; h < 2; ++h) {
            const float* wp = W + (size_t)(h * 32 + lq * 8) * 64 + 16 * t + l15;
#pragma unroll
            for (int j = 0; j < 8; ++j) {
                float wv = wp[(size_t)j * 64];
                unsigned short hi = btop(wv);
                float rem = wv - __uint_as_float((unsigned)hi << 16);
                bh[t][h][j] = (short)hi;
                bl[t][h][j] = (short)btop(rem);
            }
        }
    float av0[4], av1[4];
#pragma unroll
    for (int t = 0; t < 4; ++t) {
        av0[t] = a[16 * t + l15];
        av1[t] = a[64 + 16 * t + l15];
    }
    for (int c = wid; c < nchunk; c += nw) {
        int base = c * 16;
        f32x4 acc[4];
#pragma unroll
        for (int t = 0; t < 4; ++t) acc[t] = (f32x4){0.f, 0.f, 0.f, 0.f};
#pragma unroll
        for (int h = 0; h < 2; ++h) {
            const f32x4* xp = (const f32x4*)(X + (size_t)(base + l15) * 64 + h * 32 + lq * 8);
            f32x4 x0 = xp[0], x1 = xp[1];
            short8 ah, al;
#pragma unroll
            for (int j = 0; j < 4; ++j) {
                unsigned short h0 = btop(x0[j]);
                float r0 = x0[j] - __uint_as_float((unsigned)h0 << 16);
                ah[j] = (short)h0;
                al[j] = (short)btop(r0);
                unsigned short h1 = btop(x1[j]);
                float r1 = x1[j] - __uint_as_float((unsigned)h1 << 16);
                ah[4 + j] = (short)h1;
                al[4 + j] = (short)btop(r1);
            }
#pragma unroll
            for (int t = 0; t < 4; ++t) {
                acc[t] = __builtin_amdgcn_mfma_f32_16x16x32_bf16(ah, bh[t][h], acc[t], 0, 0, 0);
                acc[t] = __builtin_amdgcn_mfma_f32_16x16x32_bf16(ah, bl[t][h], acc[t], 0, 0, 0);
                acc[t] = __builtin_amdgcn_mfma_f32_16x16x32_bf16(al, bh[t][h], acc[t], 0, 0, 0);
            }
        }
#pragma unroll
        for (int t = 0; t < 4; ++t)
#pragma unroll
            for (int r = 0; r < 4; ++r)
                Yb[(size_t)(base + lq * 4 + r) * 64 + 16 * t + l15] = f2bf(acc[t][r]);
#pragma unroll
        for (int r = 0; r < 4; ++r) {
            float pr = acc[0][r] * av0[0] + acc[1][r] * av0[1] + acc[2][r] * av0[2] + acc[3][r] * av0[3];
            float qr = acc[0][r] * av1[0] + acc[1][r] * av1[1] + acc[2][r] * av1[2] + acc[3][r] * av1[3];
#pragma unroll
            for (int off = 8; off; off >>= 1) {
                pr += __shfl_xor(pr, off, 64);
                qr += __shfl_xor(qr, off, 64);
            }
            if (l15 == 0) {
                p[base + lq * 4 + r] = pr;
                q[base + lq * 4 + r] = qr;
            }
        }
    }
}

// ---------------- mega kernel: 5 MMF roles + ELL-scatter hist role ----------------
__global__ __launch_bounds__(256) void k_l1_fused(
        MMJob j0, MMJob j1, MMJob j2, MMJob j3, MMJob j4,
        Pats P, int* __restrict__ cnt, int* __restrict__ ell,
        int* __restrict__ ovf_gs, int* __restrict__ ovf_vx, int* __restrict__ ovf_n,
        int mmBlocks) {
    int b = blockIdx.x;
    int nm = 5 * mmBlocks;
    int lane = threadIdx.x & 63;
    if (b < nm) {
        int role = b / mmBlocks, rb = b - role * mmBlocks;
        MMJob J = (role == 0) ? j0 : (role == 1) ? j1 : (role == 2) ? j2
                : (role == 3) ? j3 : j4;
        int wid = rb * (blockDim.x >> 6) + (threadIdx.x >> 6);
        int nw = mmBlocks * (blockDim.x >> 6);
        mm_body(J.X, J.W, J.a, J.Y, J.p, J.q, J.nchunk, wid, nw, lane);
    } else {
        int hb = b - nm;
        int pidx = 0, acc = 0;
        for (; pidx < 7; ++pidx) {
            int pb = (P.E[pidx] + 255) >> 8;
            if (hb < acc + pb) break;
            acc += pb;
        }
        if (pidx >= 7) return;
        int e = (hb - acc) * 256 + threadIdx.x;
        if (e >= P.E[pidx]) return;
        int sv = P.seg[pidx][e];
        int gs = P.base[pidx] + sv;
        int vx = P.vidx[pidx][e];
        int r = atomicAdd(&cnt[gs], 1);
        int Kp = P.K[pidx];
        if (r < Kp) {
            ell[(size_t)P.eoff[pidx] + (size_t)sv * Kp + r] = vx;
        } else {
            int o = atomicAdd(ovf_n, 1);
            if (o < OVCAP) { ovf_gs[o] = gs; ovf_vx[o] = vx; }
        }
    }
}

// ---------------- dual-W / vec-proj fused MFMA body (L2) ----------------
template <int DUAL, int VEC>
__device__ __forceinline__ void mm_l2_body(const MMT& T, int lb, int nb) {
    int lane = threadIdx.x & 63;
    int l15 = lane & 15, lq = lane >> 4;
    int wid = lb * (blockDim.x >> 6) + (threadIdx.x >> 6);
    int nw = nb * (blockDim.x >> 6);

    short8 b1h[4][2], b1l[4][2], b2h[4][2], b2l[4][2];
#pragma unroll
    for (int t = 0; t < 4; ++t)
#pragma unroll
        for (int h = 0; h < 2; ++h) {
            const float* wp = T.W1 + (size_t)(h * 32 + lq * 8) * 64 + 16 * t + l15;
#pragma unroll
            for (int j = 0; j < 8; ++j) {
                float wv = wp[(size_t)j * 64];
                unsigned short hi = btop(wv);
                float rem = wv - __uint_as_float((unsigned)hi << 16);
                b1h[t][h][j] = (short)hi;
                b1l[t][h][j] = (short)btop(rem);
            }
        }
    if (DUAL) {
#pragma unroll
        for (int t = 0; t < 4; ++t)
#pragma unroll
            for (int h = 0; h < 2; ++h) {
                const float* wp = T.W2 + (size_t)(h * 32 + lq * 8) * 64 + 16 * t + l15;
#pragma unroll
                for (int j = 0; j < 8; ++j) {
                    float wv = wp[(size_t)j * 64];
                    unsigned short hi = btop(wv);
                    float rem = wv - __uint_as_float((unsigned)hi << 16);
                    b2h[t][h][j] = (short)hi;
                    b2l[t][h][j] = (short)btop(rem);
                }
            }
    }
    float a10[4], a11[4], a20[4], a21[4];
#pragma unroll
    for (int t = 0; t < 4; ++t) {
        a10[t] = T.a1[16 * t + l15];
        a11[t] = T.a1[64 + 16 * t + l15];
        if (DUAL) { a20[t] = T.a2[16 * t + l15]; a21[t] = T.a2[64 + 16 * t + l15]; }
    }
    float uv[16];
    if (VEC) {
#pragma unroll
        for (int h = 0; h < 2; ++h)
#pragma unroll
            for (int j = 0; j < 8; ++j) uv[h * 8 + j] = T.uuv[h * 32 + lq * 8 + j];
    }

    for (int c = wid; c < T.nchunk; c += nw) {
        int base = c * 16;
        f32x4 acc1[4], acc2[4];
#pragma unroll
        for (int t = 0; t < 4; ++t) {
            acc1[t] = (f32x4){0.f, 0.f, 0.f, 0.f};
            if (DUAL) acc2[t] = (f32x4){0.f, 0.f, 0.f, 0.f};
        }
        float vp = 0.f;
#pragma unroll
        for (int h = 0; h < 2; ++h) {
            const f32x4* xp = (const f32x4*)(T.X + (size_t)(base + l15) * 64 + h * 32 + lq * 8);
            f32x4 x0 = xp[0], x1 = xp[1];
            if (VEC) {
#pragma unroll
                for (int j = 0; j < 4; ++j)
                    vp += x0[j] * uv[h * 8 + j] + x1[j] * uv[h * 8 + 4 + j];
            }
            short8 ah, al;
#pragma unroll
            for (int j = 0; j < 4; ++j) {
                unsigned short h0 = btop(x0[j]);
                float r0 = x0[j] - __uint_as_float((unsigned)h0 << 16);
                ah[j] = (short)h0;
                al[j] = (short)btop(r0);
                unsigned short h1 = btop(x1[j]);
                float r1 = x1[j] - __uint_as_float((unsigned)h1 << 16);
                ah[4 + j] = (short)h1;
                al[4 + j] = (short)btop(r1);
            }
#pragma unroll
            for (int t = 0; t < 4; ++t) {
                acc1[t] = __builtin_amdgcn_mfma_f32_16x16x32_bf16(ah, b1h[t][h], acc1[t], 0, 0, 0);
                acc1[t] = __builtin_amdgcn_mfma_f32_16x16x32_bf16(ah, b1l[t][h], acc1[t], 0, 0, 0);
                acc1[t] = __builtin_amdgcn_mfma_f32_16x16x32_bf16(al, b1h[t][h], acc1[t], 0, 0, 0);
                if (DUAL) {
                    acc2[t] = __builtin_amdgcn_mfma_f32_16x16x32_bf16(ah, b2h[t][h], acc2[t], 0, 0, 0);
                    acc2[t] = __builtin_amdgcn_mfma_f32_16x16x32_bf16(ah, b2l[t][h], acc2[t], 0, 0, 0);
                    acc2[t] = __builtin_amdgcn_mfma_f32_16x16x32_bf16(al, b2h[t][h], acc2[t], 0, 0, 0);
                }
            }
        }
#pragma unroll
        for (int t = 0; t < 4; ++t)
#pragma unroll
            for (int r = 0; r < 4; ++r) {
                T.Y1[(size_t)(base + lq * 4 + r) * 64 + 16 * t + l15] = f2bf(acc1[t][r]);
                if (DUAL) T.Y2[(size_t)(base + lq * 4 + r) * 64 + 16 * t + l15] = f2bf(acc2[t][r]);
            }
#pragma unroll
        for (int r = 0; r < 4; ++r) {
            float pr = acc1[0][r] * a10[0] + acc1[1][r] * a10[1] + acc1[2][r] * a10[2] + acc1[3][r] * a10[3];
            float qr = acc1[0][r] * a11[0] + acc1[1][r] * a11[1] + acc1[2][r] * a11[2] + acc1[3][r] * a11[3];
#pragma unroll
            for (int off = 8; off; off >>= 1) {
                pr += __shfl_xor(pr, off, 64);
                qr += __shfl_xor(qr, off, 64);
            }
            if (l15 == 0) {
                T.p1[base + lq * 4 + r] = pr;
                T.q1[base + lq * 4 + r] = qr;
            }
            if (DUAL) {
                float pr2 = acc2[0][r] * a20[0] + acc2[1][r] * a20[1] + acc2[2][r] * a20[2] + acc2[3][r] * a20[3];
                float qr2 = acc2[0][r] * a21[0] + acc2[1][r] * a21[1] + acc2[2][r] * a21[2] + acc2[3][r] * a21[3];
#pragma unroll
                for (int off = 8; off; off >>= 1) {
                    pr2 += __shfl_xor(pr2, off, 64);
                    qr2 += __shfl_xor(qr2, off, 64);
                }
                if (l15 == 0) {
                    T.p2[base + lq * 4 + r] = pr2;
                    T.q2[base + lq * 4 + r] = qr2;
                }
            }
        }
        if (VEC) {
            vp += __shfl_xor(vp, 16, 64);
            vp += __shfl_xor(vp, 32, 64);
            if (lane < 16) T.pv[base + l15] = vp;
        }
    }
}

// merged L2 projection kernel
__global__ __launch_bounds__(256) void k_mm3(MMT A, MMT B, MMT C, int nb0, int nb1, int nb2) {
    int b = blockIdx.x;
    if (b < nb0) mm_l2_body<1, 0>(A, b, nb0);
    else if (b < nb0 + nb1) mm_l2_body<1, 1>(B, b - nb0, nb1);
    else mm_l2_body<0, 1>(C, b - nb0 - nb1, nb2);
}

// ---------------- segment attention gather on ELL (8 lanes/segment, 16B loads) ----------
// CH = chunks of 8 (K = CH*8). Fast path keeps logits in CH registers.
template <int CH>
__device__ __forceinline__ void seg_gather8(
    const int* __restrict__ cnt, int base, const int* __restrict__ ellp,
    int s, const float* __restrict__ ps, const float* __restrict__ pv,
    const unsigned short* __restrict__ Mb, int gl, int gbase, float* acc,
    const int* __restrict__ ovf_gs, const int* __restrict__ ovf_vx, int ovn,
    int* exv, int* ec) {
    const int K = CH * 8;
    int gs = base + s;
    int deg = cnt[gs];
    if (deg <= 0) return;
    const int* row = ellp + (size_t)s * K;
    float pss = ps[s];
    if (deg <= K) {  // fast path: logits in CH registers, 8-lane reductions
        int v0 = (gl < deg) ? row[gl] : 0;
        float l0 = (gl < deg) ? lrelu(pss + pv[v0]) : -3.4e38f;
        int v1 = 0;
        float l1 = -3.4e38f;
        if (CH == 2) {
            v1 = (8 + gl < deg) ? row[8 + gl] : 0;
            l1 = (8 + gl < deg) ? lrelu(pss + pv[v1]) : -3.4e38f;
        }
        float mx = (CH == 2) ? fmaxf(l0, l1) : l0;
#pragma unroll
        for (int off = 4; off; off >>= 1) mx = fmaxf(mx, __shfl_xor(mx, off, 64));
        float e0 = (gl < deg) ? __expf(l0 - mx) : 0.f;
        float e1 = (CH == 2 && 8 + gl < deg) ? __expf(l1 - mx) : 0.f;
        float ss = e0 + e1;
#pragma unroll
        for (int off = 4; off; off >>= 1) ss += __shfl_xor(ss, off, 64);
        float inv = 1.f / ss;
        float a0 = e0 * inv, a1 = e1 * inv;
        for (int t0 = 0; t0 < deg; t0 += 4) {   // 4 independent 16B loads in flight
            float w0, w1, w2, w3;
            int u0, u1, u2, u3;
#pragma unroll
            for (int i = 0; i < 4; ++i) {
                int t = t0 + i;
                int src = gbase + (t & 7);
                float wa = __shfl(a0, src, 64);
                int ua = __shfl(v0, src, 64);
                float wv = wa;
                int uv_ = ua;
                if (CH == 2) {
                    float wb = __shfl(a1, src, 64);
                    int ub = __shfl(v1, src, 64);
                    wv = (t < 8) ? wa : wb;
                    uv_ = (t < 8) ? ua : ub;
                }
                if (t >= deg) { wv = 0.f; uv_ = 0; }
                if (i == 0) { w0 = wv; u0 = uv_; }
                else if (i == 1) { w1 = wv; u1 = uv_; }
                else if (i == 2) { w2 = wv; u2 = uv_; }
                else { w3 = wv; u3 = uv_; }
            }
            u16x8 m0 = *(const u16x8*)(Mb + (size_t)u0 * 64 + gl * 8);
            u16x8 m1 = *(const u16x8*)(Mb + (size_t)u1 * 64 + gl * 8);
            u16x8 m2 = *(const u16x8*)(Mb + (size_t)u2 * 64 + gl * 8);
            u16x8 m3 = *(const u16x8*)(Mb + (size_t)u3 * 64 + gl * 8);
#pragma unroll
            for (int kk = 0; kk < 8; ++kk)
                acc[kk] += w0 * bf2f(m0[kk]) + w1 * bf2f(m1[kk]) +
                           w2 * bf2f(m2[kk]) + w3 * bf2f(m3[kk]);
        }
    } else {  // rare overflow path: extras from overflow list via LDS
        if (gl == 0) *ec = 0;
        for (int j = gl; j < ovn; j += 8)
            if (ovf_gs[j] == gs) { int k = atomicAdd(ec, 1); if (k < 24) exv[k] = ovf_vx[j]; }
        int m2 = min(*ec, 24);
        int total = K + m2;
        float mx = -3.4e38f;
        for (int j0 = 0; j0 < total; j0 += 8) {
            int idx = j0 + gl;
            int v = (idx < total) ? ((idx < K) ? row[idx] : exv[idx - K]) : 0;
            float l = (idx < total) ? lrelu(pss + pv[v]) : -3.4e38f;
            mx = fmaxf(mx, l);
        }
#pragma unroll
        for (int off = 4; off; off >>= 1) mx = fmaxf(mx, __shfl_xor(mx, off, 64));
        float ssum = 0.f;
        for (int j0 = 0; j0 < total; j0 += 8) {
            int idx = j0 + gl;
            int v = (idx < total) ? ((idx < K) ? row[idx] : exv[idx - K]) : 0;
            ssum += (idx < total) ? __expf(lrelu(pss + pv[v]) - mx) : 0.f;
        }
#pragma unroll
        for (int off = 4; off; off >>= 1) ssum += __shfl_xor(ssum, off, 64);
        float inv = 1.f / ssum;
        for (int j0 = 0; j0 < total; j0 += 8) {
            int idx = j0 + gl;
            int v = (idx < total) ? ((idx < K) ? row[idx] : exv[idx - K]) : 0;
            float ev = (idx < total) ? __expf(lrelu(pss + pv[v]) - mx) * inv : 0.f;
            int cc = min(8, total - j0);
            for (int t = 0; t < cc; ++t) {
                float w = __shfl(ev, gbase + t, 64);
                int vv = __shfl(v, gbase + t, 64);
                const u16x8 mv = *(const u16x8*)(Mb + (size_t)vv * 64 + gl * 8);
#pragma unroll
                for (int kk = 0; kk < 8; ++kk) acc[kk] = fmaf(w, bf2f(mv[kk]), acc[kk]);
            }
        }
    }
}

// merged 3-task AGG kernel (+ optional uu-projection role in last block)
__global__ __launch_bounds__(256) void k_agg3(
        AggTask T0, AggTask T1, AggTask T2, int nb0, int nb1, int nb2,
        const int* __restrict__ cnt, const int* __restrict__ ell,
        const int* __restrict__ ovf_gs, const int* __restrict__ ovf_vx,
        const int* __restrict__ ovf_n,
        int doUU, const float* __restrict__ WsA, const float* __restrict__ aA,
        float* __restrict__ uuA,
        const float* __restrict__ WsB, const float* __restrict__ aB,
        float* __restrict__ uuB) {
    __shared__ int exv[32][24];
    __shared__ int ec[32];
    int b = blockIdx.x;
    int nAgg = nb0 + nb1 + nb2;
    if (b >= nAgg) {
        if (!doUU || threadIdx.x >= 128) return;
        int j = threadIdx.x & 63;
        const float* W = (threadIdx.x < 64) ? WsA : WsB;
        const float* a2c = (threadIdx.x < 64) ? aA : aB;
        float* uu = (threadIdx.x < 64) ? uuA : uuB;
        float s0 = 0.f, s1 = 0.f;
        for (int k = 0; k < 64; ++k) {
            float w = W[j * 64 + k];
            s0 = fmaf(w, a2c[k], s0);
            s1 = fmaf(w, a2c[64 + k], s1);
        }
        uu[j] = s0;
        uu[64 + j] = s1;
        return;
    }
    const AggTask* T;
    int lb;
    if (b < nb0) { T = &T0; lb = b; }
    else if (b < nb0 + nb1) { T = &T1; lb = b - nb0; }
    else { T = &T2; lb = b - nb0 - nb1; }
    int lane = threadIdx.x & 63;
    int grp = threadIdx.x >> 3;          // 32 groups per block
    int g = lane >> 3, gl = lane & 7, gbase = g << 3;
    int s = (lb * (blockDim.x >> 6) + (threadIdx.x >> 6)) * 8 + g;   // 8 segs/wave
    if (s >= T->nseg) return;
    int ovn = min(*ovf_n, OVCAP);
    float acc[8];
#pragma unroll
    for (int kk = 0; kk < 8; ++kk) acc[kk] = 0.f;
    if (T->KA == 16)
        seg_gather8<2>(cnt, T->baseA, ell + T->eoffA, s, T->psA, T->pvA, T->MbA,
                       gl, gbase, acc, ovf_gs, ovf_vx, ovn, exv[grp], &ec[grp]);
    else
        seg_gather8<1>(cnt, T->baseA, ell + T->eoffA, s, T->psA, T->pvA, T->MbA,
                       gl, gbase, acc, ovf_gs, ovf_vx, ovn, exv[grp], &ec[grp]);
    if (T->baseB >= 0) {
        if (T->KB == 16)
            seg_gather8<2>(cnt, T->baseB, ell + T->eoffB, s, T->psB, T->pvB, T->MbB,
                           gl, gbase, acc, ovf_gs, ovf_vx, ovn, exv[grp], &ec[grp]);
        else
            seg_gather8<1>(cnt, T->baseB, ell + T->eoffB, s, T->psB, T->pvB, T->MbB,
                           gl, gbase, acc, ovf_gs, ovf_vx, ovn, exv[grp], &ec[grp]);
    }
    float* op = T->out + (size_t)s * 64 + gl * 8;
    *(f32x4*)op = (f32x4){acc[0], acc[1], acc[2], acc[3]};
    *(f32x4*)(op + 4) = (f32x4){acc[4], acc[5], acc[6], acc[7]};
}

extern "C" void kernel_launch(void* const* d_in, const int* in_sizes, int n_in,
                              void* d_out, int out_size, void* d_ws, size_t ws_size,
                              hipStream_t stream) {
    (void)in_sizes; (void)n_in; (void)ws_size; (void)out_size;
    const float* x0 = (const float*)d_in[0];
    const float* x1 = (const float*)d_in[1];
    const float* x2 = (const float*)d_in[2];
    const int* adj0r = (const int*)d_in[3];
    const int* adj0c = (const int*)d_in[4];
    const int* adj1r = (const int*)d_in[5];
    const int* adj1c = (const int*)d_in[6];
    const int* co2r = (const int*)d_in[7];
    const int* co2c = (const int*)d_in[8];
    const int* i1r = (const int*)d_in[9];
    const int* i1c = (const int*)d_in[10];
    const int* i2r = (const int*)d_in[11];
    const int* i2c = (const int*)d_in[12];
    const float* W_h0_l1 = (const float*)d_in[13];
    const float* W_h0_l2 = (const float*)d_in[14];
    const float* W_h1_l2 = (const float*)d_in[15];
    const float* W_h2_l2 = (const float*)d_in[16];
    const float* Ws01_l1 = (const float*)d_in[17];
    const float* Wt01_l1 = (const float*)d_in[18];
    const float* Ws12_l1 = (const float*)d_in[19];
    const float* Wt12_l1 = (const float*)d_in[20];
    const float* Ws01_l2 = (const float*)d_in[21];
    const float* Wt01_l2 = (const float*)d_in[22];
    const float* Ws12_l2 = (const float*)d_in[23];
    const float* Wt12_l2 = (const float*)d_in[24];
    const float* a_h0_l1 = (const float*)d_in[25];
    const float* a_h0_l2 = (const float*)d_in[26];
    const float* a_h1_l2 = (const float*)d_in[27];
    const float* a_h2_l2 = (const float*)d_in[28];
    const float* a01_l1 = (const float*)d_in[29];
    const float* a12_l1 = (const float*)d_in[30];
    const float* a01_l2 = (const float*)d_in[31];
    const float* a12_l2 = (const float*)d_in[32];

    // -------- workspace layout (~211 MB) --------
    float* fb = (float*)d_ws;
    float* t0 = fb;              float* t1 = t0 + 300000;
    float* t2 = t1 + 300000;     float* t3 = t2 + 300000;
    float* t4 = t3 + 300000;     float* t5 = t4 + 300000;
    float* t6 = t5 + 300000;     float* t7 = t6 + 300000;
    float* t8 = t7 + 300000;     float* t9 = t8 + 300000;
    float* t10 = t9 + 300000;
    float* uuA = t10 + 300000;   // 128
    float* uuB = uuA + 128;      // 128
    unsigned short* YA = (unsigned short*)(uuB + 128);  // [CN0*64]
    unsigned short* YB = YA + (size_t)CN0 * 64;         // [CN1*64]
    unsigned short* YC = YB + (size_t)CN1 * 64;         // [CN0*64]
    unsigned short* YD = YC + (size_t)CN0 * 64;         // [CN2*64]
    unsigned short* YE = YD + (size_t)CN2 * 64;         // [CN1*64]
    int* cnt    = (int*)(YE + (size_t)CN1 * 64);        // TOTSEG (6 MB)
    int* ell    = cnt + TOTSEG;                         // 16M ints (64 MB)
    int* ovf_gs = ell + 16000000;
    int* ovf_vx = ovf_gs + OVCAP;
    int* ovf_n  = ovf_vx + OVCAP;

    float* r0 = (float*)d_out;
    float* r1 = r0 + (size_t)CN0 * 64;
    float* r2 = r1 + (size_t)CN1 * 64;

    const int bA0 = 0;
    const int bE1 = CN0;
    const int bF1 = 2 * CN0;
    const int bE2 = 2 * CN0 + CN1;
    const int bF2 = 2 * CN0 + 2 * CN1;
    const int bA1 = 2 * CN0 + 2 * CN1 + CN2;
    const int bC2 = 2 * CN0 + 3 * CN1 + CN2;
    Pats P;
    P.seg[0] = adj0r; P.vidx[0] = adj0c; P.E[0] = EA0; P.base[0] = bA0;
    P.seg[1] = i1r;   P.vidx[1] = i1c;   P.E[1] = EB1; P.base[1] = bE1;
    P.seg[2] = i1c;   P.vidx[2] = i1r;   P.E[2] = EB1; P.base[2] = bF1;
    P.seg[3] = i2r;   P.vidx[3] = i2c;   P.E[3] = EB2; P.base[3] = bE2;
    P.seg[4] = i2c;   P.vidx[4] = i2r;   P.E[4] = EB2; P.base[4] = bF2;
    P.seg[5] = adj1r; P.vidx[5] = adj1c; P.E[5] = EA1; P.base[5] = bA1;
    P.seg[6] = co2r;  P.vidx[6] = co2c;  P.E[6] = EC2; P.base[6] = bC2;
    const int Ks[7]   = {16, 16, 8, 8, 8, 16, 8};
    const int Eoff[7] = {0, 1600000, 3200000, 5600000, 8000000, 9600000, 14400000};
    int histBlocks = 0;
    for (int p = 0; p < 7; ++p) {
        P.K[p] = Ks[p];
        P.eoff[p] = Eoff[p];
        histBlocks += (P.E[p] + 255) / 256;
    }

    // ======== stage A: ELL-scatter hist co-launched with all 5 L1 matmuls ========
    hipMemsetAsync(cnt, 0, (size_t)TOTSEG * 4, stream);
    hipMemsetAsync(ovf_n, 0, 4, stream);
    {
        const int mmBlocks = 128;
        MMJob j0 = {x0, W_h0_l1, a_h0_l1, YA, t0, t1, CN0 / 16};
        MMJob j1 = {x1, Ws01_l1, a01_l1, YB, t2, t3, CN1 / 16};
        MMJob j2 = {x0, Wt01_l1, a01_l1, YC, t4, t5, CN0 / 16};
        MMJob j3 = {x2, Ws12_l1, a12_l1, YD, t6, t7, CN2 / 16};
        MMJob j4 = {x1, Wt12_l1, a12_l1, YE, t8, t9, CN1 / 16};
        k_l1_fused<<<dim3(5 * mmBlocks + histBlocks), dim3(256), 0, stream>>>(
            j0, j1, j2, j3, j4, P, cnt, ell, ovf_gs, ovf_vx, ovf_n, mmBlocks);
    }

    // ======== stage B: merged L1 aggregations + uu projections ========
    {
        AggTask T0 = {bA0, 16, Eoff[0], t0, t1, YA,
                      bE1, 16, Eoff[1], t5, t2, YB, r0, CN0};    // x_0_to_0 + x_1_to_0
        AggTask T1 = {bF1, 8, Eoff[2], t3, t4, YC,
                      bE2, 8, Eoff[3], t9, t6, YD, r1, CN1};     // x_0_to_1 + x_2_to_1
        AggTask T2 = {bF2, 8, Eoff[4], t7, t8, YE,
                      -1, 0, 0, nullptr, nullptr, nullptr, r2, CN2};  // x_1_to_2
        int nb0 = (CN0 + 31) / 32, nb1 = (CN1 + 31) / 32, nb2 = (CN2 + 31) / 32;
        k_agg3<<<dim3(nb0 + nb1 + nb2 + 1), dim3(256), 0, stream>>>(
            T0, T1, T2, nb0, nb1, nb2, cnt, ell, ovf_gs, ovf_vx, ovf_n,
            1, Ws01_l2, a01_l2, uuA, Ws12_l2, a12_l2, uuB);
    }

    // ======== stage C: merged L2 projections (3 roles) ========
    {
        MMT A = {r0, W_h0_l2, a_h0_l2, YA, t0, t1,
                 Wt01_l2, a01_l2, YC, t4, t5, nullptr, nullptr, CN0 / 16};
        MMT B = {r1, W_h1_l2, a_h1_l2, YB, t2, t3,
                 Wt12_l2, a12_l2, YE, t8, t5, uuA + 64, t6, CN1 / 16};
        MMT C = {r2, W_h2_l2, a_h2_l2, YD, t7, t9,
                 nullptr, nullptr, nullptr, nullptr, nullptr, uuB + 64, t10, CN2 / 16};
        k_mm3<<<dim3(384 + 1024 + 640), dim3(256), 0, stream>>>(A, B, C, 384, 1024, 640);
    }

    // ======== stage D: merged L2 aggregations ========
    {
        AggTask T0 = {bA0, 16, Eoff[0], t0, t1, YA,
                      -1, 0, 0, nullptr, nullptr, nullptr, r0, CN0};  // x_0_out
        AggTask T1 = {bA1, 16, Eoff[5], t2, t3, YB,
                      bF1, 8, Eoff[2], t6, t4, YC, r1, CN1};     // x_1_to_1 + x_0_to_1
        AggTask T2 = {bC2, 8, Eoff[6], t7, t9, YD,
                      bF2, 8, Eoff[4], t10, t8, YE, r2, CN2};    // x_2_to_2 + x_1_to_2
        int nb0 = (CN0 + 31) / 32, nb1 = (CN1 + 31) / 32, nb2 = (CN2 + 31) / 32;
        k_agg3<<<dim3(nb0 + nb1 + nb2), dim3(256), 0, stream>>>(
            T0, T1, T2, nb0, nb1, nb2, cnt, ell, ovf_gs, ovf_vx, ovf_n,
            0, nullptr, nullptr, nullptr, nullptr, nullptr, nullptr);
    }
}

// Round 19
// 789.742 us; speedup vs baseline: 1.0385x; 1.0385x over previous
//
#include <hip/hip_runtime.h>

#define CN0 100000
#define CN1 300000
#define CN2 200000
#define EA0 600000
#define EA1 1200000
#define EC2 600000
#define EB1 600000
#define EB2 600000
#define TOTSEG (2*CN0 + 3*CN1 + 2*CN2)           // 1,500,000
#define OVCAP 16384

typedef __attribute__((ext_vector_type(8))) short short8;
typedef __attribute__((ext_vector_type(4))) float f32x4;
typedef __attribute__((ext_vector_type(4))) unsigned short u16x4;

__device__ __forceinline__ float lrelu(float v) { return v >= 0.f ? v : 0.2f * v; }
__device__ __forceinline__ unsigned short btop(float x) {
    return (unsigned short)(__float_as_uint(x) >> 16);
}
__device__ __forceinline__ unsigned short f2bf(float x) {  // RTN f32->bf16
    unsigned u = __float_as_uint(x);
    return (unsigned short)((u + 0x7FFFu + ((u >> 16) & 1u)) >> 16);
}
__device__ __forceinline__ float bf2f(unsigned short b) {
    return __uint_as_float((unsigned)b << 16);
}

struct Pats {
    const int* seg[7];
    const int* vidx[7];
    int E[7];
    int base[7];
    int K[7];
    int eoff[7];
};

struct MMJob {
    const float* X; const float* W; const float* a;
    unsigned short* Y; float* p; float* q; int nchunk;
};

struct MMT {
    const float* X;
    const float* W1; const float* a1; unsigned short* Y1; float* p1; float* q1;
    const float* W2; const float* a2; unsigned short* Y2; float* p2; float* q2;
    const float* uuv; float* pv; int nchunk;
};

struct AggTask {
    int baseA, KA, eoffA;
    const float* psA; const float* pvA; const unsigned short* MbA;
    int baseB, KB, eoffB;   // baseB < 0 => single-pattern task
    const float* psB; const float* pvB; const unsigned short* MbB;
    float* out; int nseg;
};

// ---------------- shared single-W MFMA body (bf16x3 split) ----------------
__device__ __forceinline__ void mm_body(const float* __restrict__ X, const float* __restrict__ W,
                                        const float* __restrict__ a, unsigned short* __restrict__ Yb,
                                        float* __restrict__ p, float* __restrict__ q,
                                        int nchunk, int wid, int nw, int lane) {
    int l15 = lane & 15, lq = lane >> 4;
    short8 bh[4][2], bl[4][2];
#pragma unroll
    for (int t = 0; t < 4; ++t)
#pragma unroll
        for (int h = 0; h < 2; ++h) {
            const float* wp = W + (size_t)(h * 32 + lq * 8) * 64 + 16 * t + l15;
#pragma unroll
            for (int j = 0; j < 8; ++j) {
                float wv = wp[(size_t)j * 64];
                unsigned short hi = btop(wv);
                float rem = wv - __uint_as_float((unsigned)hi << 16);
                bh[t][h][j] = (short)hi;
                bl[t][h][j] = (short)btop(rem);
            }
        }
    float av0[4], av1[4];
#pragma unroll
    for (int t = 0; t < 4; ++t) {
        av0[t] = a[16 * t + l15];
        av1[t] = a[64 + 16 * t + l15];
    }
    for (int c = wid; c < nchunk; c += nw) {
        int base = c * 16;
        f32x4 acc[4];
#pragma unroll
        for (int t = 0; t < 4; ++t) acc[t] = (f32x4){0.f, 0.f, 0.f, 0.f};
#pragma unroll
        for (int h = 0; h < 2; ++h) {
            const f32x4* xp = (const f32x4*)(X + (size_t)(base + l15) * 64 + h * 32 + lq * 8);
            f32x4 x0 = xp[0], x1 = xp[1];
            short8 ah, al;
#pragma unroll
            for (int j = 0; j < 4; ++j) {
                unsigned short h0 = btop(x0[j]);
                float r0 = x0[j] - __uint_as_float((unsigned)h0 << 16);
                ah[j] = (short)h0;
                al[j] = (short)btop(r0);
                unsigned short h1 = btop(x1[j]);
                float r1 = x1[j] - __uint_as_float((unsigned)h1 << 16);
                ah[4 + j] = (short)h1;
                al[4 + j] = (short)btop(r1);
            }
#pragma unroll
            for (int t = 0; t < 4; ++t) {
                acc[t] = __builtin_amdgcn_mfma_f32_16x16x32_bf16(ah, bh[t][h], acc[t], 0, 0, 0);
                acc[t] = __builtin_amdgcn_mfma_f32_16x16x32_bf16(ah, bl[t][h], acc[t], 0, 0, 0);
                acc[t] = __builtin_amdgcn_mfma_f32_16x16x32_bf16(al, bh[t][h], acc[t], 0, 0, 0);
            }
        }
#pragma unroll
        for (int t = 0; t < 4; ++t)
#pragma unroll
            for (int r = 0; r < 4; ++r)
                Yb[(size_t)(base + lq * 4 + r) * 64 + 16 * t + l15] = f2bf(acc[t][r]);
#pragma unroll
        for (int r = 0; r < 4; ++r) {
            float pr = acc[0][r] * av0[0] + acc[1][r] * av0[1] + acc[2][r] * av0[2] + acc[3][r] * av0[3];
            float qr = acc[0][r] * av1[0] + acc[1][r] * av1[1] + acc[2][r] * av1[2] + acc[3][r] * av1[3];
#pragma unroll
            for (int off = 8; off; off >>= 1) {
                pr += __shfl_xor(pr, off, 64);
                qr += __shfl_xor(qr, off, 64);
            }
            if (l15 == 0) {
                p[base + lq * 4 + r] = pr;
                q[base + lq * 4 + r] = qr;
            }
        }
    }
}

// ---------------- mega kernel: 5 MMF roles + ELL-scatter hist role ----------------
__global__ __launch_bounds__(256) void k_l1_fused(
        MMJob j0, MMJob j1, MMJob j2, MMJob j3, MMJob j4,
        Pats P, int* __restrict__ cnt, int* __restrict__ ell,
        int* __restrict__ ovf_gs, int* __restrict__ ovf_vx, int* __restrict__ ovf_n,
        int mmBlocks) {
    int b = blockIdx.x;
    int nm = 5 * mmBlocks;
    int lane = threadIdx.x & 63;
    if (b < nm) {
        int role = b / mmBlocks, rb = b - role * mmBlocks;
        MMJob J = (role == 0) ? j0 : (role == 1) ? j1 : (role == 2) ? j2
                : (role == 3) ? j3 : j4;
        int wid = rb * (blockDim.x >> 6) + (threadIdx.x >> 6);
        int nw = mmBlocks * (blockDim.x >> 6);
        mm_body(J.X, J.W, J.a, J.Y, J.p, J.q, J.nchunk, wid, nw, lane);
    } else {
        int hb = b - nm;
        int pidx = 0, acc = 0;
        for (; pidx < 7; ++pidx) {
            int pb = (P.E[pidx] + 255) >> 8;
            if (hb < acc + pb) break;
            acc += pb;
        }
        if (pidx >= 7) return;
        int e = (hb - acc) * 256 + threadIdx.x;
        if (e >= P.E[pidx]) return;
        int sv = P.seg[pidx][e];
        int gs = P.base[pidx] + sv;
        int vx = P.vidx[pidx][e];
        int r = atomicAdd(&cnt[gs], 1);
        int Kp = P.K[pidx];
        if (r < Kp) {
            ell[(size_t)P.eoff[pidx] + (size_t)sv * Kp + r] = vx;   // plain store (L2 write-combining)
        } else {
            int o = atomicAdd(ovf_n, 1);
            if (o < OVCAP) { ovf_gs[o] = gs; ovf_vx[o] = vx; }
        }
    }
}

// ---------------- dual-W / vec-proj fused MFMA body (L2) ----------------
template <int DUAL, int VEC>
__device__ __forceinline__ void mm_l2_body(const MMT& T, int lb, int nb) {
    int lane = threadIdx.x & 63;
    int l15 = lane & 15, lq = lane >> 4;
    int wid = lb * (blockDim.x >> 6) + (threadIdx.x >> 6);
    int nw = nb * (blockDim.x >> 6);

    short8 b1h[4][2], b1l[4][2], b2h[4][2], b2l[4][2];
#pragma unroll
    for (int t = 0; t < 4; ++t)
#pragma unroll
        for (int h = 0; h < 2; ++h) {
            const float* wp = T.W1 + (size_t)(h * 32 + lq * 8) * 64 + 16 * t + l15;
#pragma unroll
            for (int j = 0; j < 8; ++j) {
                float wv = wp[(size_t)j * 64];
                unsigned short hi = btop(wv);
                float rem = wv - __uint_as_float((unsigned)hi << 16);
                b1h[t][h][j] = (short)hi;
                b1l[t][h][j] = (short)btop(rem);
            }
        }
    if (DUAL) {
#pragma unroll
        for (int t = 0; t < 4; ++t)
#pragma unroll
            for (int h = 0; h < 2; ++h) {
                const float* wp = T.W2 + (size_t)(h * 32 + lq * 8) * 64 + 16 * t + l15;
#pragma unroll
                for (int j = 0; j < 8; ++j) {
                    float wv = wp[(size_t)j * 64];
                    unsigned short hi = btop(wv);
                    float rem = wv - __uint_as_float((unsigned)hi << 16);
                    b2h[t][h][j] = (short)hi;
                    b2l[t][h][j] = (short)btop(rem);
                }
            }
    }
    float a10[4], a11[4], a20[4], a21[4];
#pragma unroll
    for (int t = 0; t < 4; ++t) {
        a10[t] = T.a1[16 * t + l15];
        a11[t] = T.a1[64 + 16 * t + l15];
        if (DUAL) { a20[t] = T.a2[16 * t + l15]; a21[t] = T.a2[64 + 16 * t + l15]; }
    }
    float uv[16];
    if (VEC) {
#pragma unroll
        for (int h = 0; h < 2; ++h)
#pragma unroll
            for (int j = 0; j < 8; ++j) uv[h * 8 + j] = T.uuv[h * 32 + lq * 8 + j];
    }

    for (int c = wid; c < T.nchunk; c += nw) {
        int base = c * 16;
        f32x4 acc1[4], acc2[4];
#pragma unroll
        for (int t = 0; t < 4; ++t) {
            acc1[t] = (f32x4){0.f, 0.f, 0.f, 0.f};
            if (DUAL) acc2[t] = (f32x4){0.f, 0.f, 0.f, 0.f};
        }
        float vp = 0.f;
#pragma unroll
        for (int h = 0; h < 2; ++h) {
            const f32x4* xp = (const f32x4*)(T.X + (size_t)(base + l15) * 64 + h * 32 + lq * 8);
            f32x4 x0 = xp[0], x1 = xp[1];
            if (VEC) {
#pragma unroll
                for (int j = 0; j < 4; ++j)
                    vp += x0[j] * uv[h * 8 + j] + x1[j] * uv[h * 8 + 4 + j];
            }
            short8 ah, al;
#pragma unroll
            for (int j = 0; j < 4; ++j) {
                unsigned short h0 = btop(x0[j]);
                float r0 = x0[j] - __uint_as_float((unsigned)h0 << 16);
                ah[j] = (short)h0;
                al[j] = (short)btop(r0);
                unsigned short h1 = btop(x1[j]);
                float r1 = x1[j] - __uint_as_float((unsigned)h1 << 16);
                ah[4 + j] = (short)h1;
                al[4 + j] = (short)btop(r1);
            }
#pragma unroll
            for (int t = 0; t < 4; ++t) {
                acc1[t] = __builtin_amdgcn_mfma_f32_16x16x32_bf16(ah, b1h[t][h], acc1[t], 0, 0, 0);
                acc1[t] = __builtin_amdgcn_mfma_f32_16x16x32_bf16(ah, b1l[t][h], acc1[t], 0, 0, 0);
                acc1[t] = __builtin_amdgcn_mfma_f32_16x16x32_bf16(al, b1h[t][h], acc1[t], 0, 0, 0);
                if (DUAL) {
                    acc2[t] = __builtin_amdgcn_mfma_f32_16x16x32_bf16(ah, b2h[t][h], acc2[t], 0, 0, 0);
                    acc2[t] = __builtin_amdgcn_mfma_f32_16x16x32_bf16(ah, b2l[t][h], acc2[t], 0, 0, 0);
                    acc2[t] = __builtin_amdgcn_mfma_f32_16x16x32_bf16(al, b2h[t][h], acc2[t], 0, 0, 0);
                }
            }
        }
#pragma unroll
        for (int t = 0; t < 4; ++t)
#pragma unroll
            for (int r = 0; r < 4; ++r) {
                T.Y1[(size_t)(base + lq * 4 + r) * 64 + 16 * t + l15] = f2bf(acc1[t][r]);
                if (DUAL) T.Y2[(size_t)(base + lq * 4 + r) * 64 + 16 * t + l15] = f2bf(acc2[t][r]);
            }
#pragma unroll
        for (int r = 0; r < 4; ++r) {
            float pr = acc1[0][r] * a10[0] + acc1[1][r] * a10[1] + acc1[2][r] * a10[2] + acc1[3][r] * a10[3];
            float qr = acc1[0][r] * a11[0] + acc1[1][r] * a11[1] + acc1[2][r] * a11[2] + acc1[3][r] * a11[3];
#pragma unroll
            for (int off = 8; off; off >>= 1) {
                pr += __shfl_xor(pr, off, 64);
                qr += __shfl_xor(qr, off, 64);
            }
            if (l15 == 0) {
                T.p1[base + lq * 4 + r] = pr;
                T.q1[base + lq * 4 + r] = qr;
            }
            if (DUAL) {
                float pr2 = acc2[0][r] * a20[0] + acc2[1][r] * a20[1] + acc2[2][r] * a20[2] + acc2[3][r] * a20[3];
                float qr2 = acc2[0][r] * a21[0] + acc2[1][r] * a21[1] + acc2[2][r] * a21[2] + acc2[3][r] * a21[3];
#pragma unroll
                for (int off = 8; off; off >>= 1) {
                    pr2 += __shfl_xor(pr2, off, 64);
                    qr2 += __shfl_xor(qr2, off, 64);
                }
                if (l15 == 0) {
                    T.p2[base + lq * 4 + r] = pr2;
                    T.q2[base + lq * 4 + r] = qr2;
                }
            }
        }
        if (VEC) {
            vp += __shfl_xor(vp, 16, 64);
            vp += __shfl_xor(vp, 32, 64);
            if (lane < 16) T.pv[base + l15] = vp;
        }
    }
}

// merged L2 projection kernel
__global__ __launch_bounds__(256) void k_mm3(MMT A, MMT B, MMT C, int nb0, int nb1, int nb2) {
    int b = blockIdx.x;
    if (b < nb0) mm_l2_body<1, 0>(A, b, nb0);
    else if (b < nb0 + nb1) mm_l2_body<1, 1>(B, b - nb0, nb1);
    else mm_l2_body<0, 1>(C, b - nb0 - nb1, nb2);
}

// ---------------- segment attention gather on ELL (16 lanes/segment) ----------------
__device__ __forceinline__ void seg_gather(
    const int* __restrict__ cnt, int base, int K, const int* __restrict__ ellp,
    int s, const float* __restrict__ ps, const float* __restrict__ pv,
    const unsigned short* __restrict__ Mb, int gl, int gbase, f32x4& acc,
    const int* __restrict__ ovf_gs, const int* __restrict__ ovf_vx, int ovn,
    int* exv, int* ec) {
    int gs = base + s;
    int deg = cnt[gs];
    if (deg <= 0) return;
    const int* row = ellp + (size_t)s * K;
    float pss = ps[s];
    if (deg <= K) {  // fast path: deg <= K <= 16, single 16-wide chunk
        int v = (gl < deg) ? row[gl] : 0;
        float l = (gl < deg) ? lrelu(pss + pv[v]) : -3.4e38f;
        float mx = l;
#pragma unroll
        for (int off = 8; off; off >>= 1) mx = fmaxf(mx, __shfl_xor(mx, off, 64));
        float ev = (gl < deg) ? __expf(l - mx) : 0.f;
        float ssum = ev;
#pragma unroll
        for (int off = 8; off; off >>= 1) ssum += __shfl_xor(ssum, off, 64);
        float att = ev / ssum;
        for (int t0 = 0; t0 < deg; t0 += 4) {   // 4 independent loads in flight
            float w0 = __shfl(att, gbase + t0, 64), w1 = __shfl(att, gbase + t0 + 1, 64);
            float w2 = __shfl(att, gbase + t0 + 2, 64), w3 = __shfl(att, gbase + t0 + 3, 64);
            int u0 = __shfl(v, gbase + t0, 64), u1 = __shfl(v, gbase + t0 + 1, 64);
            int u2 = __shfl(v, gbase + t0 + 2, 64), u3 = __shfl(v, gbase + t0 + 3, 64);
            u16x4 m0 = *(const u16x4*)(Mb + (size_t)u0 * 64 + gl * 4);
            u16x4 m1 = *(const u16x4*)(Mb + (size_t)u1 * 64 + gl * 4);
            u16x4 m2 = *(const u16x4*)(Mb + (size_t)u2 * 64 + gl * 4);
            u16x4 m3 = *(const u16x4*)(Mb + (size_t)u3 * 64 + gl * 4);
#pragma unroll
            for (int kk = 0; kk < 4; ++kk)
                acc[kk] += w0 * bf2f(m0[kk]) + w1 * bf2f(m1[kk]) +
                           w2 * bf2f(m2[kk]) + w3 * bf2f(m3[kk]);
        }
    } else {  // rare overflow path
        if (gl == 0) *ec = 0;
        for (int j = gl; j < ovn; j += 16)
            if (ovf_gs[j] == gs) { int k = atomicAdd(ec, 1); if (k < 24) exv[k] = ovf_vx[j]; }
        int m2 = min(*ec, 24);
        int total = K + m2;
        float mx = -3.4e38f;
        for (int j0 = 0; j0 < total; j0 += 16) {
            int idx = j0 + gl;
            int v = (idx < total) ? ((idx < K) ? row[idx] : exv[idx - K]) : 0;
            float l = (idx < total) ? lrelu(pss + pv[v]) : -3.4e38f;
            mx = fmaxf(mx, l);
        }
#pragma unroll
        for (int off = 8; off; off >>= 1) mx = fmaxf(mx, __shfl_xor(mx, off, 64));
        float ssum = 0.f;
        for (int j0 = 0; j0 < total; j0 += 16) {
            int idx = j0 + gl;
            int v = (idx < total) ? ((idx < K) ? row[idx] : exv[idx - K]) : 0;
            ssum += (idx < total) ? __expf(lrelu(pss + pv[v]) - mx) : 0.f;
        }
#pragma unroll
        for (int off = 8; off; off >>= 1) ssum += __shfl_xor(ssum, off, 64);
        float inv = 1.f / ssum;
        for (int j0 = 0; j0 < total; j0 += 16) {
            int idx = j0 + gl;
            int v = (idx < total) ? ((idx < K) ? row[idx] : exv[idx - K]) : 0;
            float ev = (idx < total) ? __expf(lrelu(pss + pv[v]) - mx) * inv : 0.f;
            int cc = min(16, total - j0);
            for (int t = 0; t < cc; ++t) {
                float w = __shfl(ev, gbase + t, 64);
                int vv = __shfl(v, gbase + t, 64);
                const u16x4 mv = *(const u16x4*)(Mb + (size_t)vv * 64 + gl * 4);
#pragma unroll
                for (int kk = 0; kk < 4; ++kk) acc[kk] = fmaf(w, bf2f(mv[kk]), acc[kk]);
            }
        }
    }
}

// merged 3-task AGG kernel (+ optional uu-projection role in last block)
__global__ __launch_bounds__(256) void k_agg3(
        AggTask T0, AggTask T1, AggTask T2, int nb0, int nb1, int nb2,
        const int* __restrict__ cnt, const int* __restrict__ ell,
        const int* __restrict__ ovf_gs, const int* __restrict__ ovf_vx,
        const int* __restrict__ ovf_n,
        int doUU, const float* __restrict__ WsA, const float* __restrict__ aA,
        float* __restrict__ uuA,
        const float* __restrict__ WsB, const float* __restrict__ aB,
        float* __restrict__ uuB) {
    __shared__ int exv[16][24];
    __shared__ int ec[16];
    int b = blockIdx.x;
    int nAgg = nb0 + nb1 + nb2;
    if (b >= nAgg) {
        if (!doUU || threadIdx.x >= 128) return;
        int j = threadIdx.x & 63;
        const float* W = (threadIdx.x < 64) ? WsA : WsB;
        const float* a2c = (threadIdx.x < 64) ? aA : aB;
        float* uu = (threadIdx.x < 64) ? uuA : uuB;
        float s0 = 0.f, s1 = 0.f;
        for (int k = 0; k < 64; ++k) {
            float w = W[j * 64 + k];
            s0 = fmaf(w, a2c[k], s0);
            s1 = fmaf(w, a2c[64 + k], s1);
        }
        uu[j] = s0;
        uu[64 + j] = s1;
        return;
    }
    const AggTask* T;
    int lb;
    if (b < nb0) { T = &T0; lb = b; }
    else if (b < nb0 + nb1) { T = &T1; lb = b - nb0; }
    else { T = &T2; lb = b - nb0 - nb1; }
    int lane = threadIdx.x & 63;
    int grp = threadIdx.x >> 4;
    int g = lane >> 4, gl = lane & 15, gbase = g << 4;
    int s = (lb * (blockDim.x >> 6) + (threadIdx.x >> 6)) * 4 + g;
    if (s >= T->nseg) return;
    int ovn = min(*ovf_n, OVCAP);
    f32x4 acc = (f32x4){0.f, 0.f, 0.f, 0.f};
    seg_gather(cnt, T->baseA, T->KA, ell + T->eoffA, s, T->psA, T->pvA, T->MbA,
               gl, gbase, acc, ovf_gs, ovf_vx, ovn, exv[grp], &ec[grp]);
    if (T->baseB >= 0)
        seg_gather(cnt, T->baseB, T->KB, ell + T->eoffB, s, T->psB, T->pvB, T->MbB,
                   gl, gbase, acc, ovf_gs, ovf_vx, ovn, exv[grp], &ec[grp]);
    *(f32x4*)(T->out + (size_t)s * 64 + gl * 4) = acc;
}

extern "C" void kernel_launch(void* const* d_in, const int* in_sizes, int n_in,
                              void* d_out, int out_size, void* d_ws, size_t ws_size,
                              hipStream_t stream) {
    (void)in_sizes; (void)n_in; (void)ws_size; (void)out_size;
    const float* x0 = (const float*)d_in[0];
    const float* x1 = (const float*)d_in[1];
    const float* x2 = (const float*)d_in[2];
    const int* adj0r = (const int*)d_in[3];
    const int* adj0c = (const int*)d_in[4];
    const int* adj1r = (const int*)d_in[5];
    const int* adj1c = (const int*)d_in[6];
    const int* co2r = (const int*)d_in[7];
    const int* co2c = (const int*)d_in[8];
    const int* i1r = (const int*)d_in[9];
    const int* i1c = (const int*)d_in[10];
    const int* i2r = (const int*)d_in[11];
    const int* i2c = (const int*)d_in[12];
    const float* W_h0_l1 = (const float*)d_in[13];
    const float* W_h0_l2 = (const float*)d_in[14];
    const float* W_h1_l2 = (const float*)d_in[15];
    const float* W_h2_l2 = (const float*)d_in[16];
    const float* Ws01_l1 = (const float*)d_in[17];
    const float* Wt01_l1 = (const float*)d_in[18];
    const float* Ws12_l1 = (const float*)d_in[19];
    const float* Wt12_l1 = (const float*)d_in[20];
    const float* Ws01_l2 = (const float*)d_in[21];
    const float* Wt01_l2 = (const float*)d_in[22];
    const float* Ws12_l2 = (const float*)d_in[23];
    const float* Wt12_l2 = (const float*)d_in[24];
    const float* a_h0_l1 = (const float*)d_in[25];
    const float* a_h0_l2 = (const float*)d_in[26];
    const float* a_h1_l2 = (const float*)d_in[27];
    const float* a_h2_l2 = (const float*)d_in[28];
    const float* a01_l1 = (const float*)d_in[29];
    const float* a12_l1 = (const float*)d_in[30];
    const float* a01_l2 = (const float*)d_in[31];
    const float* a12_l2 = (const float*)d_in[32];

    // -------- workspace layout (~211 MB) --------
    float* fb = (float*)d_ws;
    float* t0 = fb;              float* t1 = t0 + 300000;
    float* t2 = t1 + 300000;     float* t3 = t2 + 300000;
    float* t4 = t3 + 300000;     float* t5 = t4 + 300000;
    float* t6 = t5 + 300000;     float* t7 = t6 + 300000;
    float* t8 = t7 + 300000;     float* t9 = t8 + 300000;
    float* t10 = t9 + 300000;
    float* uuA = t10 + 300000;   // 128
    float* uuB = uuA + 128;      // 128
    unsigned short* YA = (unsigned short*)(uuB + 128);  // [CN0*64]
    unsigned short* YB = YA + (size_t)CN0 * 64;         // [CN1*64]
    unsigned short* YC = YB + (size_t)CN1 * 64;         // [CN0*64]
    unsigned short* YD = YC + (size_t)CN0 * 64;         // [CN2*64]
    unsigned short* YE = YD + (size_t)CN2 * 64;         // [CN1*64]
    int* cnt    = (int*)(YE + (size_t)CN1 * 64);        // TOTSEG (6 MB)
    int* ell    = cnt + TOTSEG;                         // 16M ints (64 MB)
    int* ovf_gs = ell + 16000000;
    int* ovf_vx = ovf_gs + OVCAP;
    int* ovf_n  = ovf_vx + OVCAP;

    float* r0 = (float*)d_out;
    float* r1 = r0 + (size_t)CN0 * 64;
    float* r2 = r1 + (size_t)CN1 * 64;

    const int bA0 = 0;
    const int bE1 = CN0;
    const int bF1 = 2 * CN0;
    const int bE2 = 2 * CN0 + CN1;
    const int bF2 = 2 * CN0 + 2 * CN1;
    const int bA1 = 2 * CN0 + 2 * CN1 + CN2;
    const int bC2 = 2 * CN0 + 3 * CN1 + CN2;
    Pats P;
    P.seg[0] = adj0r; P.vidx[0] = adj0c; P.E[0] = EA0; P.base[0] = bA0;
    P.seg[1] = i1r;   P.vidx[1] = i1c;   P.E[1] = EB1; P.base[1] = bE1;
    P.seg[2] = i1c;   P.vidx[2] = i1r;   P.E[2] = EB1; P.base[2] = bF1;
    P.seg[3] = i2r;   P.vidx[3] = i2c;   P.E[3] = EB2; P.base[3] = bE2;
    P.seg[4] = i2c;   P.vidx[4] = i2r;   P.E[4] = EB2; P.base[4] = bF2;
    P.seg[5] = adj1r; P.vidx[5] = adj1c; P.E[5] = EA1; P.base[5] = bA1;
    P.seg[6] = co2r;  P.vidx[6] = co2c;  P.E[6] = EC2; P.base[6] = bC2;
    const int Ks[7]   = {16, 16, 8, 8, 8, 16, 8};
    const int Eoff[7] = {0, 1600000, 3200000, 5600000, 8000000, 9600000, 14400000};
    int histBlocks = 0;
    for (int p = 0; p < 7; ++p) {
        P.K[p] = Ks[p];
        P.eoff[p] = Eoff[p];
        histBlocks += (P.E[p] + 255) / 256;
    }

    // ======== stage A: ELL-scatter hist co-launched with all 5 L1 matmuls ========
    hipMemsetAsync(cnt, 0, (size_t)TOTSEG * 4, stream);
    hipMemsetAsync(ovf_n, 0, 4, stream);
    {
        const int mmBlocks = 128;
        MMJob j0 = {x0, W_h0_l1, a_h0_l1, YA, t0, t1, CN0 / 16};
        MMJob j1 = {x1, Ws01_l1, a01_l1, YB, t2, t3, CN1 / 16};
        MMJob j2 = {x0, Wt01_l1, a01_l1, YC, t4, t5, CN0 / 16};
        MMJob j3 = {x2, Ws12_l1, a12_l1, YD, t6, t7, CN2 / 16};
        MMJob j4 = {x1, Wt12_l1, a12_l1, YE, t8, t9, CN1 / 16};
        k_l1_fused<<<dim3(5 * mmBlocks + histBlocks), dim3(256), 0, stream>>>(
            j0, j1, j2, j3, j4, P, cnt, ell, ovf_gs, ovf_vx, ovf_n, mmBlocks);
    }

    // ======== stage B: merged L1 aggregations + uu projections ========
    {
        AggTask T0 = {bA0, 16, Eoff[0], t0, t1, YA,
                      bE1, 16, Eoff[1], t5, t2, YB, r0, CN0};    // x_0_to_0 + x_1_to_0
        AggTask T1 = {bF1, 8, Eoff[2], t3, t4, YC,
                      bE2, 8, Eoff[3], t9, t6, YD, r1, CN1};     // x_0_to_1 + x_2_to_1
        AggTask T2 = {bF2, 8, Eoff[4], t7, t8, YE,
                      -1, 0, 0, nullptr, nullptr, nullptr, r2, CN2};  // x_1_to_2
        int nb0 = (CN0 + 15) / 16, nb1 = (CN1 + 15) / 16, nb2 = (CN2 + 15) / 16;
        k_agg3<<<dim3(nb0 + nb1 + nb2 + 1), dim3(256), 0, stream>>>(
            T0, T1, T2, nb0, nb1, nb2, cnt, ell, ovf_gs, ovf_vx, ovf_n,
            1, Ws01_l2, a01_l2, uuA, Ws12_l2, a12_l2, uuB);
    }

    // ======== stage C: merged L2 projections (3 roles) ========
    {
        MMT A = {r0, W_h0_l2, a_h0_l2, YA, t0, t1,
                 Wt01_l2, a01_l2, YC, t4, t5, nullptr, nullptr, CN0 / 16};
        MMT B = {r1, W_h1_l2, a_h1_l2, YB, t2, t3,
                 Wt12_l2, a12_l2, YE, t8, t5, uuA + 64, t6, CN1 / 16};
        MMT C = {r2, W_h2_l2, a_h2_l2, YD, t7, t9,
                 nullptr, nullptr, nullptr, nullptr, nullptr, uuB + 64, t10, CN2 / 16};
        k_mm3<<<dim3(384 + 1024 + 640), dim3(256), 0, stream>>>(A, B, C, 384, 1024, 640);
    }

    // ======== stage D: merged L2 aggregations ========
    {
        AggTask T0 = {bA0, 16, Eoff[0], t0, t1, YA,
                      -1, 0, 0, nullptr, nullptr, nullptr, r0, CN0};  // x_0_out
        AggTask T1 = {bA1, 16, Eoff[5], t2, t3, YB,
                      bF1, 8, Eoff[2], t6, t4, YC, r1, CN1};     // x_1_to_1 + x_0_to_1
        AggTask T2 = {bC2, 8, Eoff[6], t7, t9, YD,
                      bF2, 8, Eoff[4], t10, t8, YE, r2, CN2};    // x_2_to_2 + x_1_to_2
        int nb0 = (CN0 + 15) / 16, nb1 = (CN1 + 15) / 16, nb2 = (CN2 + 15) / 16;
        k_agg3<<<dim3(nb0 + nb1 + nb2), dim3(256), 0, stream>>>(
            T0, T1, T2, nb0, nb1, nb2, cnt, ell, ovf_gs, ovf_vx, ovf_n,
            0, nullptr, nullptr, nullptr, nullptr, nullptr, nullptr);
    }
}